// Round 1
// baseline (309.427 us; speedup 1.0000x reference)
//
#include <hip/hip_runtime.h>
#include <hip/hip_bf16.h>
#include <stdint.h>
#include <stddef.h>

typedef __bf16 bf16_t;
typedef __bf16 bf16x8 __attribute__((ext_vector_type(8)));
typedef __bf16 bf16x4 __attribute__((ext_vector_type(4)));
typedef float  f32x4  __attribute__((ext_vector_type(4)));

#define T_SEQ 2032
#define T_PAD 2048
#define DM    1408
#define NHEAD 16
#define HD    88
#define HP    96
#define SM_SCALE 0.10660035817780521f   // 88^-0.5

// -------- async global->LDS (16B per lane, wave-uniform LDS base) --------
__device__ __forceinline__ void gload_lds16(const bf16_t* g, bf16_t* l) {
  __builtin_amdgcn_global_load_lds(
      (__attribute__((address_space(1))) void*)(g),
      (__attribute__((address_space(3))) void*)(l), 16, 0, 0);
}

// ---------------- convert x (f32 [2032][1408]) -> bf16 [2048][1408], pad 0
__global__ void k_convert_x(const float* __restrict__ x, bf16_t* __restrict__ Xb) {
  int idx = blockIdx.x * 256 + threadIdx.x;            // one per 4 elems
  const int total = T_PAD * DM / 4;
  if (idx >= total) return;
  int base = idx * 4;
  int t = base / DM;
  float4 v;
  if (t < T_SEQ) v = *(const float4*)(x + base);
  else           v = make_float4(0.f, 0.f, 0.f, 0.f);
  bf16x4 o;
  o[0] = (bf16_t)v.x; o[1] = (bf16_t)v.y; o[2] = (bf16_t)v.z; o[3] = (bf16_t)v.w;
  *(bf16x4*)(Xb + base) = o;
}

// ---------------- tiled transpose + f32->bf16: src[R][C] f32 -> dst[C][R] bf16
__global__ void k_transpose_conv(const float* __restrict__ src, bf16_t* __restrict__ dst,
                                 int R, int C) {
  __shared__ float tile[32][33];
  const int tiles_c = C >> 5;
  const int tr = blockIdx.x / tiles_c;
  const int tc = blockIdx.x % tiles_c;
  const int lane = threadIdx.x & 31;
  const int row  = threadIdx.x >> 5;      // 0..7
#pragma unroll
  for (int i = 0; i < 32; i += 8)
    tile[row + i][lane] = src[(size_t)(tr * 32 + row + i) * C + tc * 32 + lane];
  __syncthreads();
#pragma unroll
  for (int i = 0; i < 32; i += 8)
    dst[(size_t)(tc * 32 + row + i) * R + tr * 32 + lane] = (bf16_t)tile[lane][row + i];
}

// ---------------- concat biases (bq|bk|bv) -> f32[4224]
__global__ void k_bias(const float* __restrict__ bq, const float* __restrict__ bk,
                       const float* __restrict__ bv, float* __restrict__ bias) {
  int i = blockIdx.x * 256 + threadIdx.x;
  if (i >= 3 * DM) return;
  bias[i] = (i < DM) ? bq[i] : ((i < 2 * DM) ? bk[i - DM] : bv[i - 2 * DM]);
}

// ---------------- RoPE in place on Qh/Kh ([16][2048][96]); Q also * sm_scale
__global__ void k_rope(bf16_t* __restrict__ Q, bf16_t* __restrict__ K,
                       const float* __restrict__ freqs) {
  int idx = blockIdx.x * 256 + threadIdx.x;
  const int TOT = 2 * NHEAD * T_SEQ * 44;
  if (idx >= TOT) return;
  int i = idx % 44;
  int t = (idx / 44) % T_SEQ;
  int n = (idx / (44 * T_SEQ)) % NHEAD;
  int which = idx / (44 * T_SEQ * NHEAD);
  bf16_t* P = (which ? K : Q) + ((size_t)n * T_PAD + t) * HP + 2 * i;
  float c = freqs[t * 88 + 2 * i];
  float s = freqs[t * 88 + 2 * i + 1];
  float x1 = (float)P[0], x2 = (float)P[1];
  float sc = which ? 1.0f : SM_SCALE;
  P[0] = (bf16_t)((x1 * c - x2 * s) * sc);
  P[1] = (bf16_t)((x1 * s + x2 * c) * sc);
}

// ---------------- shared GEMM mainloop: C128x128 tile, BK=32, K=1408, 4 waves
__device__ __forceinline__ void gemm_main_1408(
    const bf16_t* __restrict__ A, const bf16_t* __restrict__ Bt,
    bf16_t* As, bf16_t* Bs, int m0, int n0, f32x4 acc[4][4]) {
  const int tid = threadIdx.x;
  const int w = tid >> 6, lane = tid & 63;
  const int l15 = lane & 15, lg = lane >> 4;
  const int b0 = w * 2048 + lane * 16;           // byte offset in 8KB tile, pass 0
  const int r0 = b0 >> 6, k0 = (b0 & 63) >> 1;
  const int b1 = b0 + 1024;                      // pass 1
  const int r1 = b1 >> 6, k1 = (b1 & 63) >> 1;
  const int wr = w >> 1, wc = w & 1;
  const size_t aoff0 = (size_t)(m0 + r0) * DM + k0;
  const size_t aoff1 = (size_t)(m0 + r1) * DM + k1;
  const size_t boff0 = (size_t)(n0 + r0) * DM + k0;
  const size_t boff1 = (size_t)(n0 + r1) * DM + k1;
  for (int kt = 0; kt < 44; ++kt) {
    const int ko = kt * 32;
    gload_lds16(A + aoff0 + ko, As + w * 1024);
    gload_lds16(A + aoff1 + ko, As + w * 1024 + 512);
    gload_lds16(Bt + boff0 + ko, Bs + w * 1024);
    gload_lds16(Bt + boff1 + ko, Bs + w * 1024 + 512);
    __syncthreads();
    bf16x8 av[4], bv[4];
#pragma unroll
    for (int m = 0; m < 4; ++m)
      av[m] = *(const bf16x8*)(As + (wr * 64 + m * 16 + l15) * 32 + lg * 8);
#pragma unroll
    for (int n = 0; n < 4; ++n)
      bv[n] = *(const bf16x8*)(Bs + (wc * 64 + n * 16 + l15) * 32 + lg * 8);
#pragma unroll
    for (int m = 0; m < 4; ++m)
#pragma unroll
      for (int n = 0; n < 4; ++n)
        acc[m][n] = __builtin_amdgcn_mfma_f32_16x16x32_bf16(av[m], bv[n], acc[m][n], 0, 0, 0);
    __syncthreads();
  }
}

// ---------------- GEMM 1: X[2048][1408] @ Wqkv^T[4224][1408] -> scatter Q/K/V
__global__ __launch_bounds__(256, 2) void k_gemm_qkv(
    const bf16_t* __restrict__ A, const bf16_t* __restrict__ Bt,
    const float* __restrict__ bias,
    bf16_t* __restrict__ Qh, bf16_t* __restrict__ Kh, bf16_t* __restrict__ Vt) {
  __shared__ bf16_t As[128 * 32];
  __shared__ bf16_t Bs[128 * 32];
  const int mt = blockIdx.x / 33, nt = blockIdx.x % 33;
  f32x4 acc[4][4];
#pragma unroll
  for (int m = 0; m < 4; ++m)
#pragma unroll
    for (int n = 0; n < 4; ++n) acc[m][n] = (f32x4){0.f, 0.f, 0.f, 0.f};
  gemm_main_1408(A, Bt, As, Bs, mt * 128, nt * 128, acc);
  const int tid = threadIdx.x, w = tid >> 6, lane = tid & 63;
  const int l15 = lane & 15, lg = lane >> 4;
  const int wr = w >> 1, wc = w & 1;
  const int cb = nt * 128 + wc * 64, rb = mt * 128 + wr * 64;
#pragma unroll
  for (int n = 0; n < 4; ++n) {
    const int col = cb + n * 16 + l15;
    const float bv = bias[col];
    const int seg = (col >= 2 * DM) ? 2 : ((col >= DM) ? 1 : 0);
    const int cc = col - seg * DM;
    const int hn = cc / 88;
    const int hh = cc - hn * 88;
#pragma unroll
    for (int m = 0; m < 4; ++m) {
#pragma unroll
      for (int r = 0; r < 4; ++r) {
        const int t = rb + m * 16 + lg * 4 + r;
        const bf16_t bb = (bf16_t)(acc[m][n][r] + bv);
        if (seg == 0)      Qh[((size_t)hn * T_PAD + t) * HP + hh] = bb;
        else if (seg == 1) Kh[((size_t)hn * T_PAD + t) * HP + hh] = bb;
        else               Vt[((size_t)hn * HP + hh) * T_PAD + t] = bb;
      }
    }
  }
}

// ---------------- GEMM 2: attnout[2048][1408] @ Wo^T[1408][1408] + bo -> f32 out
__global__ __launch_bounds__(256, 2) void k_gemm_out(
    const bf16_t* __restrict__ A, const bf16_t* __restrict__ Bt,
    const float* __restrict__ bo, float* __restrict__ out) {
  __shared__ bf16_t As[128 * 32];
  __shared__ bf16_t Bs[128 * 32];
  const int mt = blockIdx.x / 11, nt = blockIdx.x % 11;
  f32x4 acc[4][4];
#pragma unroll
  for (int m = 0; m < 4; ++m)
#pragma unroll
    for (int n = 0; n < 4; ++n) acc[m][n] = (f32x4){0.f, 0.f, 0.f, 0.f};
  gemm_main_1408(A, Bt, As, Bs, mt * 128, nt * 128, acc);
  const int tid = threadIdx.x, w = tid >> 6, lane = tid & 63;
  const int l15 = lane & 15, lg = lane >> 4;
  const int wr = w >> 1, wc = w & 1;
  const int cb = nt * 128 + wc * 64, rb = mt * 128 + wr * 64;
#pragma unroll
  for (int n = 0; n < 4; ++n) {
    const int col = cb + n * 16 + l15;
    const float bv = bo[col];
#pragma unroll
    for (int m = 0; m < 4; ++m) {
#pragma unroll
      for (int r = 0; r < 4; ++r) {
        const int t = rb + m * 16 + lg * 4 + r;
        if (t < T_SEQ) out[(size_t)t * DM + col] = acc[m][n][r] + bv;
      }
    }
  }
}

// ---------------- flash attention: 1 WG = (head, 64 q rows), 4 waves x 16 rows
__global__ __launch_bounds__(256, 2) void k_attn(
    const bf16_t* __restrict__ Qh, const bf16_t* __restrict__ Kh,
    const bf16_t* __restrict__ Vt, bf16_t* __restrict__ Ob) {
  __shared__ bf16_t Ks[128 * HP];     // [s][h]  24576 B
  __shared__ bf16_t Vs[HP * 128];     // [h][s]  24576 B
  __shared__ bf16_t Ps[4][16 * 128];  // per-wave P tile, 16384 B
  const int tid = threadIdx.x;
  const int w = tid >> 6, lane = tid & 63;
  const int l15 = lane & 15, lg = lane >> 4;
  const int head = blockIdx.x >> 5;
  const int qt = blockIdx.x & 31;
  const bf16_t* Qn = Qh + (size_t)head * T_PAD * HP;
  const bf16_t* Kn = Kh + (size_t)head * T_PAD * HP;
  const bf16_t* Vn = Vt + (size_t)head * HP * T_PAD;
  const int q0 = qt * 64 + w * 16;

  bf16x8 qf[3];
#pragma unroll
  for (int kh = 0; kh < 3; ++kh)
    qf[kh] = *(const bf16x8*)(Qn + (size_t)(q0 + l15) * HP + kh * 32 + lg * 8);

  f32x4 oacc[6];
#pragma unroll
  for (int j = 0; j < 6; ++j) oacc[j] = (f32x4){0.f, 0.f, 0.f, 0.f};
  float mrow[4] = {-1e30f, -1e30f, -1e30f, -1e30f};
  float lrow[4] = {0.f, 0.f, 0.f, 0.f};

  int krow[6], koff[6], vrow[6], voff[6];
#pragma unroll
  for (int p = 0; p < 6; ++p) {
    int b = (w * 6 + p) * 1024 + lane * 16;
    krow[p] = b / 192;  koff[p] = (b % 192) >> 1;
    vrow[p] = b >> 8;   voff[p] = (b & 255) >> 1;
  }

  for (int kvt = 0; kvt < 16; ++kvt) {
    const int s0 = kvt * 128;
#pragma unroll
    for (int p = 0; p < 6; ++p) {
      gload_lds16(Kn + (size_t)(s0 + krow[p]) * HP + koff[p], Ks + (w * 6 + p) * 512);
      gload_lds16(Vn + (size_t)vrow[p] * T_PAD + s0 + voff[p], Vs + (w * 6 + p) * 512);
    }
    __syncthreads();

    // S = Q @ K^T  (16 x 128)
    f32x4 sf[8];
#pragma unroll
    for (int ss = 0; ss < 8; ++ss) {
      f32x4 s = {0.f, 0.f, 0.f, 0.f};
#pragma unroll
      for (int kh = 0; kh < 3; ++kh) {
        bf16x8 kf = *(const bf16x8*)(Ks + (ss * 16 + l15) * HP + kh * 32 + lg * 8);
        s = __builtin_amdgcn_mfma_f32_16x16x32_bf16(qf[kh], kf, s, 0, 0, 0);
      }
      if (s0 + ss * 16 + l15 >= T_SEQ) s = (f32x4){-1e30f, -1e30f, -1e30f, -1e30f};
      sf[ss] = s;
    }
    // online softmax (rows live in regs r, cols across the 16-lane group)
    float tm[4];
#pragma unroll
    for (int r = 0; r < 4; ++r) {
      float v = sf[0][r];
#pragma unroll
      for (int ss = 1; ss < 8; ++ss) v = fmaxf(v, sf[ss][r]);
      tm[r] = v;
    }
#pragma unroll
    for (int d = 1; d < 16; d <<= 1)
#pragma unroll
      for (int r = 0; r < 4; ++r) tm[r] = fmaxf(tm[r], __shfl_xor(tm[r], d, 16));
    float sc[4];
#pragma unroll
    for (int r = 0; r < 4; ++r) {
      float mn = fmaxf(mrow[r], tm[r]);
      sc[r] = __expf(mrow[r] - mn);
      mrow[r] = mn;
    }
    float rs[4] = {0.f, 0.f, 0.f, 0.f};
#pragma unroll
    for (int ss = 0; ss < 8; ++ss)
#pragma unroll
      for (int r = 0; r < 4; ++r) {
        float p = __expf(sf[ss][r] - mrow[r]);
        sf[ss][r] = p;
        rs[r] += p;
      }
#pragma unroll
    for (int d = 1; d < 16; d <<= 1)
#pragma unroll
      for (int r = 0; r < 4; ++r) rs[r] += __shfl_xor(rs[r], d, 16);
#pragma unroll
    for (int r = 0; r < 4; ++r) lrow[r] = lrow[r] * sc[r] + rs[r];
#pragma unroll
    for (int j = 0; j < 6; ++j)
#pragma unroll
      for (int r = 0; r < 4; ++r) oacc[j][r] *= sc[r];
    // P (C-layout) -> LDS in A-layout order
#pragma unroll
    for (int ss = 0; ss < 8; ++ss)
#pragma unroll
      for (int r = 0; r < 4; ++r)
        Ps[w][(lg * 4 + r) * 128 + ss * 16 + l15] = (bf16_t)sf[ss][r];
    // O += P @ V
#pragma unroll
    for (int j = 0; j < 6; ++j)
#pragma unroll
      for (int ks = 0; ks < 4; ++ks) {
        bf16x8 pa = *(const bf16x8*)(&Ps[w][l15 * 128 + ks * 32 + lg * 8]);
        bf16x8 vf = *(const bf16x8*)(Vs + (j * 16 + l15) * 128 + ks * 32 + lg * 8);
        oacc[j] = __builtin_amdgcn_mfma_f32_16x16x32_bf16(pa, vf, oacc[j], 0, 0, 0);
      }
    __syncthreads();
  }
  // write attention output, [t][n*88+h] bf16
#pragma unroll
  for (int j = 0; j < 6; ++j) {
    const int h = j * 16 + l15;
    if (h < HD) {
#pragma unroll
      for (int r = 0; r < 4; ++r) {
        const int t = q0 + lg * 4 + r;
        if (t < T_SEQ)
          Ob[(size_t)t * DM + head * HD + h] = (bf16_t)(oacc[j][r] / lrow[r]);
      }
    }
  }
}

// ---------------- host side ----------------
extern "C" void kernel_launch(void* const* d_in, const int* in_sizes, int n_in,
                              void* d_out, int out_size, void* d_ws, size_t ws_size,
                              hipStream_t stream) {
  (void)in_sizes; (void)n_in; (void)out_size; (void)ws_size;
  const float* x     = (const float*)d_in[0];
  const float* freqs = (const float*)d_in[1];
  const float* Wq    = (const float*)d_in[2];
  const float* bq    = (const float*)d_in[3];
  const float* Wk    = (const float*)d_in[4];
  const float* bk    = (const float*)d_in[5];
  const float* Wv    = (const float*)d_in[6];
  const float* bv    = (const float*)d_in[7];
  const float* Wo    = (const float*)d_in[8];
  const float* bo    = (const float*)d_in[9];
  float* out = (float*)d_out;
  char* ws = (char*)d_ws;

  // workspace layout (peak ~36.6 MB); Xb reused as Ob, Wt reused as Wo^T
  bf16_t* Xb   = (bf16_t*)(ws);                       //  5,767,168 B
  bf16_t* Wt   = (bf16_t*)(ws + 5767168);             // 11,894,784 B
  float*  bias = (float*) (ws + 17661952);            //     16,896 B
  bf16_t* Qh   = (bf16_t*)(ws + 17678848);            //  6,291,456 B
  bf16_t* Kh   = (bf16_t*)(ws + 23970304);            //  6,291,456 B
  bf16_t* Vt   = (bf16_t*)(ws + 30261760);            //  6,291,456 B
  bf16_t* Ob   = Xb;
  bf16_t* Wot  = Wt;

  // zero Q/K pads (h=88..95 must contribute 0 to scores)
  hipMemsetAsync(Qh, 0, 2 * 6291456, stream);

  k_convert_x<<<(T_PAD * DM / 4 + 255) / 256, 256, 0, stream>>>(x, Xb);
  k_transpose_conv<<<44 * 44, 256, 0, stream>>>(Wq, Wt,                 DM, DM);
  k_transpose_conv<<<44 * 44, 256, 0, stream>>>(Wk, Wt + (size_t)DM*DM, DM, DM);
  k_transpose_conv<<<44 * 44, 256, 0, stream>>>(Wv, Wt + (size_t)2*DM*DM, DM, DM);
  k_bias<<<(3 * DM + 255) / 256, 256, 0, stream>>>(bq, bk, bv, bias);

  k_gemm_qkv<<<16 * 33, 256, 0, stream>>>(Xb, Wt, bias, Qh, Kh, Vt);
  k_rope<<<(2 * NHEAD * T_SEQ * 44 + 255) / 256, 256, 0, stream>>>(Qh, Kh, freqs);

  // Wo transpose reuses Wt space (Wqkv^T dead after k_gemm_qkv)
  k_transpose_conv<<<44 * 44, 256, 0, stream>>>(Wo, Wot, DM, DM);

  k_attn<<<NHEAD * 32, 256, 0, stream>>>(Qh, Kh, Vt, Ob);
  k_gemm_out<<<16 * 11, 256, 0, stream>>>(Ob, Wot, bo, out);
}

// Round 2
// 255.621 us; speedup vs baseline: 1.2105x; 1.2105x over previous
//
#include <hip/hip_runtime.h>
#include <hip/hip_bf16.h>
#include <stdint.h>
#include <stddef.h>

typedef __bf16 bf16_t;
typedef __bf16 bf16x8 __attribute__((ext_vector_type(8)));
typedef __bf16 bf16x4 __attribute__((ext_vector_type(4)));
typedef float  f32x4  __attribute__((ext_vector_type(4)));

#define T_SEQ 2032
#define T_PAD 2048
#define DM    1408
#define NHEAD 16
#define HD    88
#define HPQ   96     // Q global row stride (bf16 elems)
#define HPK   128    // K global row stride (256B rows -> XOR-swizzlable)
#define HPV   96     // V padded head rows
#define SM_SCALE 0.10660035817780521f   // 88^-0.5

// -------- async global->LDS (16B per lane, wave-uniform LDS base) --------
__device__ __forceinline__ void gload_lds16(const bf16_t* g, bf16_t* l) {
  __builtin_amdgcn_global_load_lds(
      (__attribute__((address_space(1))) void*)(g),
      (__attribute__((address_space(3))) void*)(l), 16, 0, 0);
}

// ---------------- convert x (f32 [2032][1408]) -> bf16 [2048][1408], pad 0
__global__ void k_convert_x(const float* __restrict__ x, bf16_t* __restrict__ Xb) {
  int idx = blockIdx.x * 256 + threadIdx.x;
  const int total = T_PAD * DM / 4;
  if (idx >= total) return;
  int base = idx * 4;
  int t = base / DM;
  float4 v;
  if (t < T_SEQ) v = *(const float4*)(x + base);
  else           v = make_float4(0.f, 0.f, 0.f, 0.f);
  bf16x4 o;
  o[0] = (bf16_t)v.x; o[1] = (bf16_t)v.y; o[2] = (bf16_t)v.z; o[3] = (bf16_t)v.w;
  *(bf16x4*)(Xb + base) = o;
}

// ---------------- tiled transpose + f32->bf16: src[R][C] f32 -> dst[C][R] bf16
__device__ __forceinline__ void transpose_body(const float* __restrict__ src,
                                               bf16_t* __restrict__ dst,
                                               int R, int C, int blk) {
  __shared__ float tile[32][33];
  const int tiles_c = C >> 5;
  const int tr = blk / tiles_c;
  const int tc = blk % tiles_c;
  const int lane = threadIdx.x & 31;
  const int row  = threadIdx.x >> 5;
#pragma unroll
  for (int i = 0; i < 32; i += 8)
    tile[row + i][lane] = src[(size_t)(tr * 32 + row + i) * C + tc * 32 + lane];
  __syncthreads();
#pragma unroll
  for (int i = 0; i < 32; i += 8)
    dst[(size_t)(tc * 32 + row + i) * R + tr * 32 + lane] = (bf16_t)tile[lane][row + i];
}

__global__ void k_transpose3(const float* __restrict__ Wq, const float* __restrict__ Wk,
                             const float* __restrict__ Wv, bf16_t* __restrict__ dst) {
  const int which = blockIdx.x / 1936;
  const int b = blockIdx.x % 1936;
  const float* src = (which == 0) ? Wq : (which == 1) ? Wk : Wv;
  transpose_body(src, dst + (size_t)which * DM * DM, DM, DM, b);
}

__global__ void k_transpose1(const float* __restrict__ src, bf16_t* __restrict__ dst) {
  transpose_body(src, dst, DM, DM, blockIdx.x);
}

// ---------------- concat biases (bq|bk|bv) -> f32[4224]
__global__ void k_bias(const float* __restrict__ bq, const float* __restrict__ bk,
                       const float* __restrict__ bv, float* __restrict__ bias) {
  int i = blockIdx.x * 256 + threadIdx.x;
  if (i >= 3 * DM) return;
  bias[i] = (i < DM) ? bq[i] : ((i < 2 * DM) ? bk[i - DM] : bv[i - 2 * DM]);
}

// ---------------- RoPE in place; Q (stride 96) also * sm_scale, K stride 128
__global__ void k_rope(bf16_t* __restrict__ Q, bf16_t* __restrict__ K,
                       const float* __restrict__ freqs) {
  int idx = blockIdx.x * 256 + threadIdx.x;
  const int TOT = 2 * NHEAD * T_SEQ * 44;
  if (idx >= TOT) return;
  int i = idx % 44;
  int t = (idx / 44) % T_SEQ;
  int n = (idx / (44 * T_SEQ)) % NHEAD;
  int which = idx / (44 * T_SEQ * NHEAD);
  bf16_t* P = which ? (K + ((size_t)n * T_PAD + t) * HPK + 2 * i)
                    : (Q + ((size_t)n * T_PAD + t) * HPQ + 2 * i);
  float c = freqs[t * 88 + 2 * i];
  float s = freqs[t * 88 + 2 * i + 1];
  float x1 = (float)P[0], x2 = (float)P[1];
  float sc = which ? 1.0f : SM_SCALE;
  P[0] = (bf16_t)((x1 * c - x2 * s) * sc);
  P[1] = (bf16_t)((x1 * s + x2 * c) * sc);
}

// ---------------- shared GEMM mainloop: C128x128 tile, BK=32, K=1408, 4 waves
__device__ __forceinline__ void gemm_main_1408(
    const bf16_t* __restrict__ A, const bf16_t* __restrict__ Bt,
    bf16_t* As, bf16_t* Bs, int m0, int n0, f32x4 acc[4][4]) {
  const int tid = threadIdx.x;
  const int w = tid >> 6, lane = tid & 63;
  const int l15 = lane & 15, lg = lane >> 4;
  const int b0 = w * 2048 + lane * 16;
  const int r0 = b0 >> 6, k0 = (b0 & 63) >> 1;
  const int b1 = b0 + 1024;
  const int r1 = b1 >> 6, k1 = (b1 & 63) >> 1;
  const int wr = w >> 1, wc = w & 1;
  const size_t aoff0 = (size_t)(m0 + r0) * DM + k0;
  const size_t aoff1 = (size_t)(m0 + r1) * DM + k1;
  const size_t boff0 = (size_t)(n0 + r0) * DM + k0;
  const size_t boff1 = (size_t)(n0 + r1) * DM + k1;
  for (int kt = 0; kt < 44; ++kt) {
    const int ko = kt * 32;
    gload_lds16(A + aoff0 + ko, As + w * 1024);
    gload_lds16(A + aoff1 + ko, As + w * 1024 + 512);
    gload_lds16(Bt + boff0 + ko, Bs + w * 1024);
    gload_lds16(Bt + boff1 + ko, Bs + w * 1024 + 512);
    __syncthreads();
    bf16x8 av[4], bv[4];
#pragma unroll
    for (int m = 0; m < 4; ++m)
      av[m] = *(const bf16x8*)(As + (wr * 64 + m * 16 + l15) * 32 + lg * 8);
#pragma unroll
    for (int n = 0; n < 4; ++n)
      bv[n] = *(const bf16x8*)(Bs + (wc * 64 + n * 16 + l15) * 32 + lg * 8);
#pragma unroll
    for (int m = 0; m < 4; ++m)
#pragma unroll
      for (int n = 0; n < 4; ++n)
        acc[m][n] = __builtin_amdgcn_mfma_f32_16x16x32_bf16(av[m], bv[n], acc[m][n], 0, 0, 0);
    __syncthreads();
  }
}

// ---------------- GEMM 1: X[2048][1408] @ Wqkv^T[4224][1408] -> scatter Q/K/V
__global__ __launch_bounds__(256, 2) void k_gemm_qkv(
    const bf16_t* __restrict__ A, const bf16_t* __restrict__ Bt,
    const float* __restrict__ bias,
    bf16_t* __restrict__ Qh, bf16_t* __restrict__ Kh, bf16_t* __restrict__ Vt) {
  __shared__ bf16_t As[128 * 32];
  __shared__ bf16_t Bs[128 * 32];
  const int mt = blockIdx.x / 33, nt = blockIdx.x % 33;
  f32x4 acc[4][4];
#pragma unroll
  for (int m = 0; m < 4; ++m)
#pragma unroll
    for (int n = 0; n < 4; ++n) acc[m][n] = (f32x4){0.f, 0.f, 0.f, 0.f};
  gemm_main_1408(A, Bt, As, Bs, mt * 128, nt * 128, acc);
  const int tid = threadIdx.x, w = tid >> 6, lane = tid & 63;
  const int l15 = lane & 15, lg = lane >> 4;
  const int wr = w >> 1, wc = w & 1;
  const int cb = nt * 128 + wc * 64, rb = mt * 128 + wr * 64;
#pragma unroll
  for (int n = 0; n < 4; ++n) {
    const int col = cb + n * 16 + l15;
    const float bv = bias[col];
    const int seg = (col >= 2 * DM) ? 2 : ((col >= DM) ? 1 : 0);
    const int cc = col - seg * DM;
    const int hn = cc / 88;
    const int hh = cc - hn * 88;
#pragma unroll
    for (int m = 0; m < 4; ++m) {
      const int tb = rb + m * 16 + lg * 4;
      if (seg == 2) {
        bf16x4 vv;
#pragma unroll
        for (int r = 0; r < 4; ++r) vv[r] = (bf16_t)(acc[m][n][r] + bv);
        *(bf16x4*)(Vt + ((size_t)hn * HPV + hh) * T_PAD + tb) = vv;
      } else if (seg == 0) {
#pragma unroll
        for (int r = 0; r < 4; ++r)
          Qh[((size_t)hn * T_PAD + tb + r) * HPQ + hh] = (bf16_t)(acc[m][n][r] + bv);
      } else {
#pragma unroll
        for (int r = 0; r < 4; ++r)
          Kh[((size_t)hn * T_PAD + tb + r) * HPK + hh] = (bf16_t)(acc[m][n][r] + bv);
      }
    }
  }
}

// ---------------- GEMM 2: attnout[2048][1408] @ Wo^T + bo -> f32 out, BM=64
__global__ __launch_bounds__(256, 2) void k_gemm_out64(
    const bf16_t* __restrict__ A, const bf16_t* __restrict__ Bt,
    const float* __restrict__ bo, float* __restrict__ out) {
  __shared__ bf16_t Sm[6144];   // A[64][32] @0, B[128][32] @2048
  const int mt = blockIdx.x / 11, nt = blockIdx.x % 11;
  const int m0 = mt * 64, n0 = nt * 128;
  const int tid = threadIdx.x, w = tid >> 6, lane = tid & 63;
  const int l15 = lane & 15, lg = lane >> 4;
  const bf16_t* srcp[3];
  size_t srco[3];
  int dste[3];
#pragma unroll
  for (int p = 0; p < 3; ++p) {
    const int off = w * 3072 + p * 1024;
    const int o = off + lane * 16;
    dste[p] = off >> 1;
    if (off < 4096) {
      int r = o >> 6, k = (o & 63) >> 1;
      srcp[p] = A; srco[p] = (size_t)(m0 + r) * DM + k;
    } else {
      int ob = o - 4096;
      int r = ob >> 6, k = (ob & 63) >> 1;
      srcp[p] = Bt; srco[p] = (size_t)(n0 + r) * DM + k;
    }
  }
  f32x4 acc[4][2];
#pragma unroll
  for (int m = 0; m < 4; ++m)
#pragma unroll
    for (int n = 0; n < 2; ++n) acc[m][n] = (f32x4){0.f, 0.f, 0.f, 0.f};
  for (int kt = 0; kt < 44; ++kt) {
    const int ko = kt * 32;
#pragma unroll
    for (int p = 0; p < 3; ++p)
      gload_lds16(srcp[p] + srco[p] + ko, Sm + dste[p]);
    __syncthreads();
    bf16x8 av[4], bv2[2];
#pragma unroll
    for (int m = 0; m < 4; ++m)
      av[m] = *(const bf16x8*)(Sm + (m * 16 + l15) * 32 + lg * 8);
#pragma unroll
    for (int n = 0; n < 2; ++n)
      bv2[n] = *(const bf16x8*)(Sm + 2048 + (w * 32 + n * 16 + l15) * 32 + lg * 8);
#pragma unroll
    for (int m = 0; m < 4; ++m)
#pragma unroll
      for (int n = 0; n < 2; ++n)
        acc[m][n] = __builtin_amdgcn_mfma_f32_16x16x32_bf16(av[m], bv2[n], acc[m][n], 0, 0, 0);
    __syncthreads();
  }
  const int cb = n0 + w * 32;
#pragma unroll
  for (int n = 0; n < 2; ++n) {
    const int col = cb + n * 16 + l15;
    const float bv = bo[col];
#pragma unroll
    for (int m = 0; m < 4; ++m) {
#pragma unroll
      for (int r = 0; r < 4; ++r) {
        const int t = m0 + m * 16 + lg * 4 + r;
        if (t < T_SEQ) out[(size_t)t * DM + col] = acc[m][n][r] + bv;
      }
    }
  }
}

// ---------------- flash attention: 1 WG = (head, 64 q rows), 4 waves x 16 rows
// All LDS tiles 256B rows with chunk^(row&7) XOR swizzle -> conflict-free reads.
__global__ __launch_bounds__(256, 2) void k_attn(
    const bf16_t* __restrict__ Qh, const bf16_t* __restrict__ Kh,
    const bf16_t* __restrict__ Vt, bf16_t* __restrict__ Ob) {
  __shared__ bf16_t Ks[128 * 128];    // [s][h] swizzled, 32KB
  __shared__ bf16_t Vs[HPV * 128];    // [h][s] swizzled, 24KB
  __shared__ bf16_t Ps[4][16 * 128];  // per-wave P, swizzled, 16KB
  const int tid = threadIdx.x;
  const int w = tid >> 6, lane = tid & 63;
  const int l15 = lane & 15, lg = lane >> 4;
  const int swz = l15 & 7;
  const int head = blockIdx.x >> 5;
  const int qt = blockIdx.x & 31;
  const bf16_t* Qn = Qh + (size_t)head * T_PAD * HPQ;
  const bf16_t* Kn = Kh + (size_t)head * T_PAD * HPK;
  const bf16_t* Vn = Vt + (size_t)head * HPV * T_PAD;
  const int q0 = qt * 64 + w * 16;

  bf16x8 qf[3];
#pragma unroll
  for (int kh = 0; kh < 3; ++kh)
    qf[kh] = *(const bf16x8*)(Qn + (size_t)(q0 + l15) * HPQ + kh * 32 + lg * 8);

  f32x4 oacc[6];
#pragma unroll
  for (int j = 0; j < 6; ++j) oacc[j] = (f32x4){0.f, 0.f, 0.f, 0.f};
  float mrow[4] = {-1e30f, -1e30f, -1e30f, -1e30f};
  float lrow[4] = {0.f, 0.f, 0.f, 0.f};

  // pre-swizzled staging source offsets (dest LDS stays linear)
  int ko_e[8];
#pragma unroll
  for (int p = 0; p < 8; ++p) {
    int o = (w * 8 + p) * 1024 + lane * 16;
    int row = o >> 8, ch = (o >> 4) & 15;
    ko_e[p] = row * HPK + ((ch ^ (row & 7)) << 3);
  }
  int vo_e[6];
#pragma unroll
  for (int p = 0; p < 6; ++p) {
    int o = (w * 6 + p) * 1024 + lane * 16;
    int row = o >> 8, ch = (o >> 4) & 15;
    vo_e[p] = row * T_PAD + ((ch ^ (row & 7)) << 3);
  }

  for (int kvt = 0; kvt < 16; ++kvt) {
    const int s0 = kvt * 128;
#pragma unroll
    for (int p = 0; p < 8; ++p)
      gload_lds16(Kn + (size_t)s0 * HPK + ko_e[p], Ks + (w * 8 + p) * 512);
#pragma unroll
    for (int p = 0; p < 6; ++p)
      gload_lds16(Vn + s0 + vo_e[p], Vs + (w * 6 + p) * 512);
    __syncthreads();

    // S = Q @ K^T  (16 x 128)
    f32x4 sf[8];
#pragma unroll
    for (int ss = 0; ss < 8; ++ss) {
      const int rowK = ss * 16 + l15;
      f32x4 s = {0.f, 0.f, 0.f, 0.f};
#pragma unroll
      for (int kh = 0; kh < 3; ++kh) {
        bf16x8 kf = *(const bf16x8*)(Ks + rowK * 128 + (((kh * 4 + lg) ^ swz) << 3));
        s = __builtin_amdgcn_mfma_f32_16x16x32_bf16(qf[kh], kf, s, 0, 0, 0);
      }
      if (s0 + rowK >= T_SEQ) s = (f32x4){-1e30f, -1e30f, -1e30f, -1e30f};
      sf[ss] = s;
    }
    // online softmax (rows in regs r, cols across the 16-lane group)
    float tm[4];
#pragma unroll
    for (int r = 0; r < 4; ++r) {
      float v = sf[0][r];
#pragma unroll
      for (int ss = 1; ss < 8; ++ss) v = fmaxf(v, sf[ss][r]);
      tm[r] = v;
    }
#pragma unroll
    for (int d = 1; d < 16; d <<= 1)
#pragma unroll
      for (int r = 0; r < 4; ++r) tm[r] = fmaxf(tm[r], __shfl_xor(tm[r], d, 16));
    float sc[4];
#pragma unroll
    for (int r = 0; r < 4; ++r) {
      float mn = fmaxf(mrow[r], tm[r]);
      sc[r] = __expf(mrow[r] - mn);
      mrow[r] = mn;
    }
    float rs[4] = {0.f, 0.f, 0.f, 0.f};
#pragma unroll
    for (int ss = 0; ss < 8; ++ss)
#pragma unroll
      for (int r = 0; r < 4; ++r) {
        float p = __expf(sf[ss][r] - mrow[r]);
        sf[ss][r] = p;
        rs[r] += p;
      }
#pragma unroll
    for (int d = 1; d < 16; d <<= 1)
#pragma unroll
      for (int r = 0; r < 4; ++r) rs[r] += __shfl_xor(rs[r], d, 16);
#pragma unroll
    for (int r = 0; r < 4; ++r) lrow[r] = lrow[r] * sc[r] + rs[r];
#pragma unroll
    for (int j = 0; j < 6; ++j)
#pragma unroll
      for (int r = 0; r < 4; ++r) oacc[j][r] *= sc[r];
    // P (C-layout) -> LDS in swizzled A-layout
#pragma unroll
    for (int ss = 0; ss < 8; ++ss)
#pragma unroll
      for (int r = 0; r < 4; ++r) {
        const int row = lg * 4 + r;
        Ps[w][row * 128 + (((2 * ss + (l15 >> 3)) ^ (row & 7)) << 3) + (l15 & 7)] =
            (bf16_t)sf[ss][r];
      }
    // O += P @ V
    bf16x8 pa[4];
#pragma unroll
    for (int ks = 0; ks < 4; ++ks)
      pa[ks] = *(const bf16x8*)(&Ps[w][l15 * 128 + (((ks * 4 + lg) ^ swz) << 3)]);
#pragma unroll
    for (int j = 0; j < 6; ++j)
#pragma unroll
      for (int ks = 0; ks < 4; ++ks) {
        bf16x8 vf = *(const bf16x8*)(Vs + (j * 16 + l15) * 128 + (((ks * 4 + lg) ^ swz) << 3));
        oacc[j] = __builtin_amdgcn_mfma_f32_16x16x32_bf16(pa[ks], vf, oacc[j], 0, 0, 0);
      }
    __syncthreads();
  }
  // write attention output, [t][n*88+h] bf16
#pragma unroll
  for (int j = 0; j < 6; ++j) {
    const int h = j * 16 + l15;
    if (h < HD) {
#pragma unroll
      for (int r = 0; r < 4; ++r) {
        const int t = q0 + lg * 4 + r;
        if (t < T_SEQ)
          Ob[(size_t)t * DM + head * HD + h] = (bf16_t)(oacc[j][r] / lrow[r]);
      }
    }
  }
}

// ---------------- host side ----------------
extern "C" void kernel_launch(void* const* d_in, const int* in_sizes, int n_in,
                              void* d_out, int out_size, void* d_ws, size_t ws_size,
                              hipStream_t stream) {
  (void)in_sizes; (void)n_in; (void)out_size; (void)ws_size;
  const float* x     = (const float*)d_in[0];
  const float* freqs = (const float*)d_in[1];
  const float* Wq    = (const float*)d_in[2];
  const float* bq    = (const float*)d_in[3];
  const float* Wk    = (const float*)d_in[4];
  const float* bk    = (const float*)d_in[5];
  const float* Wv    = (const float*)d_in[6];
  const float* bv    = (const float*)d_in[7];
  const float* Wo    = (const float*)d_in[8];
  const float* bo    = (const float*)d_in[9];
  float* out = (float*)d_out;
  char* ws = (char*)d_ws;

  // workspace layout (38.7 MB); Xb reused as Ob, Wt reused as Wo^T
  bf16_t* Xb   = (bf16_t*)(ws);                       //  5,767,168 B
  bf16_t* Wt   = (bf16_t*)(ws + 5767168);             // 11,894,784 B
  float*  bias = (float*) (ws + 17661952);            //     16,896 B
  bf16_t* Qh   = (bf16_t*)(ws + 17678848);            //  6,291,456 B (stride 96)
  bf16_t* Kh   = (bf16_t*)(ws + 23970304);            //  8,388,608 B (stride 128)
  bf16_t* Vt   = (bf16_t*)(ws + 32358912);            //  6,291,456 B
  bf16_t* Ob   = Xb;
  bf16_t* Wot  = Wt;

  // zero Q (pads incl. rows>=T_SEQ) and K: 6,291,456 + 8,388,608 (adjacent)
  hipMemsetAsync(Qh, 0, 14680064, stream);

  k_convert_x<<<(T_PAD * DM / 4 + 255) / 256, 256, 0, stream>>>(x, Xb);
  k_transpose3<<<3 * 1936, 256, 0, stream>>>(Wq, Wk, Wv, Wt);
  k_bias<<<17, 256, 0, stream>>>(bq, bk, bv, bias);

  k_gemm_qkv<<<16 * 33, 256, 0, stream>>>(Xb, Wt, bias, Qh, Kh, Vt);
  k_rope<<<2 * NHEAD * T_SEQ * 44 / 256, 256, 0, stream>>>(Qh, Kh, freqs);

  // Wo transpose reuses Wt space (Wqkv^T dead after k_gemm_qkv)
  k_transpose1<<<1936, 256, 0, stream>>>(Wo, Wot);

  k_attn<<<NHEAD * 32, 256, 0, stream>>>(Qh, Kh, Vt, Ob);
  k_gemm_out64<<<32 * 11, 256, 0, stream>>>(Ob, Wot, bo, out);
}